// Round 1
// baseline (525.304 us; speedup 1.0000x reference)
//
#include <hip/hip_runtime.h>
#include <math.h>

#define B 8192
#define D 512
#define NH 4
#define M 128
#define W 64
#define HW 256   // NH * W
#define EPS 1e-6f

// ---------------------------------------------------------------------------
// K1: key = tanh(hidden @ W_key + b_key)  -> key_ws [B][256]
// Thread j (0..255) owns output column j; each workgroup owns 16 batch rows.
// hidden[i][d] is wave-uniform -> expect scalar (s_load) path; W_key read is
// coalesced across threads and L2-resident (512 KB).
// ---------------------------------------------------------------------------
__global__ __launch_bounds__(256) void key_gemm(const float* __restrict__ hid,
                                                const float* __restrict__ Wk,
                                                const float* __restrict__ bk,
                                                float* __restrict__ key) {
    const int j  = threadIdx.x;
    const int i0 = blockIdx.x * 16;
    float acc[16];
#pragma unroll
    for (int ii = 0; ii < 16; ++ii) acc[ii] = 0.f;
    const float* hbase = hid + (size_t)i0 * D;
    for (int d = 0; d < D; ++d) {
        const float w = Wk[(size_t)d * HW + j];
#pragma unroll
        for (int ii = 0; ii < 16; ++ii)
            acc[ii] = fmaf(hbase[(size_t)ii * D + d], w, acc[ii]);
    }
    const float bj = bk[j];
#pragma unroll
    for (int ii = 0; ii < 16; ++ii)
        key[(size_t)(i0 + ii) * HW + j] = tanhf(acc[ii] + bj);
}

// ---------------------------------------------------------------------------
// K2: beta = softplus(hidden @ W_beta + b_beta) -> beta_ws [B][4]
// ---------------------------------------------------------------------------
__global__ __launch_bounds__(256) void beta_kernel(const float* __restrict__ hid,
                                                   const float* __restrict__ Wb,
                                                   const float* __restrict__ bb,
                                                   float* __restrict__ beta) {
    const int t = blockIdx.x * blockDim.x + threadIdx.x;  // t < B*NH
    const int b = t >> 2;
    const int h = t & 3;
    float acc = 0.f;
    const float* hrow = hid + (size_t)b * D;
    for (int d = 0; d < D; ++d)
        acc = fmaf(hrow[d], Wb[(size_t)d * NH + h], acc);
    const float x = acc + bb[h];
    // numerically stable softplus: max(x,0) + log1p(exp(-|x|))
    beta[t] = fmaxf(x, 0.f) + log1pf(expf(-fabsf(x)));
}

// ---------------------------------------------------------------------------
// K3: cosine similarity + scaled softmax.
// One block of 128 threads (2 waves) per batch; thread m owns memory row m.
// ---------------------------------------------------------------------------
__global__ __launch_bounds__(128) void attn_kernel(const float* __restrict__ mem,
                                                   const float* __restrict__ key,
                                                   const float* __restrict__ beta,
                                                   float* __restrict__ out) {
    const int b = blockIdx.x;
    const int t = threadIdx.x;  // row index m

    __shared__ float ksh[HW];
    __shared__ float u2sh[NH];
    __shared__ float bsh[NH];
    __shared__ float red[2][NH];

    ksh[t]       = key[(size_t)b * HW + t];
    ksh[t + 128] = key[(size_t)b * HW + t + 128];
    if (t < NH) bsh[t] = beta[(size_t)b * NH + t];
    __syncthreads();

    if (t < NH) {
        float s = 0.f;
#pragma unroll
        for (int w = 0; w < W; ++w) {
            const float kv = ksh[t * W + w];
            s = fmaf(kv, kv, s);
        }
        u2sh[t] = s + EPS;
    }
    __syncthreads();

    // num[h] = key[h,:] . mem[b,m,:];  v2 = |mem row|^2
    const float4* row = (const float4*)(mem + (size_t)b * (M * W) + (size_t)t * W);
    float v2 = 0.f;
    float nh[NH] = {0.f, 0.f, 0.f, 0.f};
#pragma unroll
    for (int c = 0; c < 16; ++c) {
        const float4 x = row[c];
        v2 = fmaf(x.x, x.x, fmaf(x.y, x.y, fmaf(x.z, x.z, fmaf(x.w, x.w, v2))));
#pragma unroll
        for (int h = 0; h < NH; ++h) {
            const float4 kk = *(const float4*)&ksh[h * W + c * 4];
            nh[h] = fmaf(x.x, kk.x, fmaf(x.y, kk.y, fmaf(x.z, kk.z, fmaf(x.w, kk.w, nh[h]))));
        }
    }
    v2 += EPS;

    float logit[NH];
#pragma unroll
    for (int h = 0; h < NH; ++h) {
        const float den = sqrtf(u2sh[h] * v2);
        logit[h] = (nh[h] / (den + EPS)) * bsh[h];
    }

    // softmax over m (= thread index), per head; 2 waves -> shuffle + LDS combine
    const int lane = t & 63;
    const int wid  = t >> 6;

    float mx[NH];
#pragma unroll
    for (int h = 0; h < NH; ++h) {
        float m_ = logit[h];
#pragma unroll
        for (int off = 1; off < 64; off <<= 1)
            m_ = fmaxf(m_, __shfl_xor(m_, off, 64));
        mx[h] = m_;
    }
    if (lane == 0) {
#pragma unroll
        for (int h = 0; h < NH; ++h) red[wid][h] = mx[h];
    }
    __syncthreads();

    float e[NH];
#pragma unroll
    for (int h = 0; h < NH; ++h) {
        const float gm = fmaxf(red[0][h], red[1][h]);
        e[h] = expf(logit[h] - gm);
    }
    __syncthreads();  // everyone done reading red before it is overwritten

    float sm[NH];
#pragma unroll
    for (int h = 0; h < NH; ++h) {
        float s_ = e[h];
#pragma unroll
        for (int off = 1; off < 64; off <<= 1)
            s_ += __shfl_xor(s_, off, 64);
        sm[h] = s_;
    }
    if (lane == 0) {
#pragma unroll
        for (int h = 0; h < NH; ++h) red[wid][h] = sm[h];
    }
    __syncthreads();

#pragma unroll
    for (int h = 0; h < NH; ++h) {
        const float tot = red[0][h] + red[1][h];
        out[(size_t)b * (NH * M) + (size_t)h * M + t] = e[h] / tot;
    }
}

// ---------------------------------------------------------------------------
extern "C" void kernel_launch(void* const* d_in, const int* in_sizes, int n_in,
                              void* d_out, int out_size, void* d_ws, size_t ws_size,
                              hipStream_t stream) {
    const float* hid = (const float*)d_in[0];  // [B, D]
    const float* mem = (const float*)d_in[1];  // [B, M, W]
    const float* Wk  = (const float*)d_in[2];  // [D, HW]
    const float* bk  = (const float*)d_in[3];  // [HW]
    const float* Wb  = (const float*)d_in[4];  // [D, NH]
    const float* bb  = (const float*)d_in[5];  // [NH]
    float* out = (float*)d_out;                // [B, NH, M]

    float* key_ws  = (float*)d_ws;                    // B*HW floats (8 MB)
    float* beta_ws = key_ws + (size_t)B * HW;         // B*NH floats

    key_gemm<<<B / 16, 256, 0, stream>>>(hid, Wk, bk, key_ws);
    beta_kernel<<<(B * NH) / 256, 256, 0, stream>>>(hid, Wb, bb, beta_ws);
    attn_kernel<<<B, 128, 0, stream>>>(mem, key_ws, beta_ws, out);
}

// Round 2
// 523.464 us; speedup vs baseline: 1.0035x; 1.0035x over previous
//
#include <hip/hip_runtime.h>
#include <math.h>

#define B 8192
#define D 512
#define NH 4
#define M 128
#define W 64
#define HW 256   // NH * W
#define EPS 1e-6f

// ---------------------------------------------------------------------------
// K1: key = tanh(hidden @ W_key + b_key)   -> key_ws  [B][256]
//     beta = softplus(hidden @ W_beta+b_b) -> beta_ws [B][4]   (fused)
// Thread j (0..255) owns key column j; each workgroup owns 16 batch rows.
// hidden[i][d] is wave-uniform in the main loop -> scalar (s_load) path;
// W_key read is coalesced across threads and L2-resident (512 KB).
// Beta tail: threads repartition as (row ii, head h, quarter q) -> 128-FMA
// partial dot over d in [q*128,(q+1)*128), reduced across q via shfl_xor.
// hidden re-read for the tail hits L2 (just streamed).
// ---------------------------------------------------------------------------
__global__ __launch_bounds__(256) void key_beta_gemm(const float* __restrict__ hid,
                                                     const float* __restrict__ Wk,
                                                     const float* __restrict__ bk,
                                                     const float* __restrict__ Wb,
                                                     const float* __restrict__ bb,
                                                     float* __restrict__ key,
                                                     float* __restrict__ beta) {
    const int j  = threadIdx.x;
    const int i0 = blockIdx.x * 16;
    const float* hbase = hid + (size_t)i0 * D;

    float acc[16];
#pragma unroll
    for (int ii = 0; ii < 16; ++ii) acc[ii] = 0.f;

    for (int d = 0; d < D; ++d) {
        const float w = Wk[(size_t)d * HW + j];
#pragma unroll
        for (int ii = 0; ii < 16; ++ii)
            acc[ii] = fmaf(hbase[(size_t)ii * D + d], w, acc[ii]);
    }
    const float bj = bk[j];
#pragma unroll
    for (int ii = 0; ii < 16; ++ii)
        key[(size_t)(i0 + ii) * HW + j] = tanhf(acc[ii] + bj);

    // ---- fused beta tail -------------------------------------------------
    const int ii = j >> 4;        // row 0..15
    const int h  = (j >> 2) & 3;  // head 0..3
    const int q  = j & 3;         // quarter of D
    const float* hrow = hbase + (size_t)ii * D + q * 128;
    const float* wcol = Wb + (size_t)q * 128 * NH + h;
    float acc2 = 0.f;
#pragma unroll 4
    for (int d = 0; d < 128; ++d)
        acc2 = fmaf(hrow[d], wcol[(size_t)d * NH], acc2);
    acc2 += __shfl_xor(acc2, 1, 64);
    acc2 += __shfl_xor(acc2, 2, 64);
    if (q == 0) {
        const float x = acc2 + bb[h];
        // stable softplus: max(x,0) + log1p(exp(-|x|))
        beta[(size_t)(i0 + ii) * NH + h] = fmaxf(x, 0.f) + log1pf(expf(-fabsf(x)));
    }
}

// ---------------------------------------------------------------------------
// K2: cosine similarity + scaled softmax.
// One block of 128 threads (2 waves) per batch; thread m owns memory row m.
// Row loads are 16 x float4 fully unrolled -> all 4 lines per lane in flight
// together (full line utilization), memory-bound at the 268 MB stream.
// ---------------------------------------------------------------------------
__global__ __launch_bounds__(128) void attn_kernel(const float* __restrict__ mem,
                                                   const float* __restrict__ key,
                                                   const float* __restrict__ beta,
                                                   float* __restrict__ out) {
    const int b = blockIdx.x;
    const int t = threadIdx.x;  // row index m

    __shared__ float ksh[HW];
    __shared__ float u2sh[NH];
    __shared__ float bsh[NH];
    __shared__ float red[2][NH];

    ksh[t]       = key[(size_t)b * HW + t];
    ksh[t + 128] = key[(size_t)b * HW + t + 128];
    if (t < NH) bsh[t] = beta[(size_t)b * NH + t];
    __syncthreads();

    if (t < NH) {
        float s = 0.f;
#pragma unroll
        for (int w = 0; w < W; ++w) {
            const float kv = ksh[t * W + w];
            s = fmaf(kv, kv, s);
        }
        u2sh[t] = s + EPS;
    }
    __syncthreads();

    // num[h] = key[h,:] . mem[b,m,:];  v2 = |mem row|^2
    const float4* row = (const float4*)(mem + (size_t)b * (M * W) + (size_t)t * W);
    float v2 = 0.f;
    float nh[NH] = {0.f, 0.f, 0.f, 0.f};
#pragma unroll
    for (int c = 0; c < 16; ++c) {
        const float4 x = row[c];
        v2 = fmaf(x.x, x.x, fmaf(x.y, x.y, fmaf(x.z, x.z, fmaf(x.w, x.w, v2))));
#pragma unroll
        for (int h = 0; h < NH; ++h) {
            const float4 kk = *(const float4*)&ksh[h * W + c * 4];
            nh[h] = fmaf(x.x, kk.x, fmaf(x.y, kk.y, fmaf(x.z, kk.z, fmaf(x.w, kk.w, nh[h]))));
        }
    }
    v2 += EPS;

    float logit[NH];
#pragma unroll
    for (int h = 0; h < NH; ++h) {
        const float den = sqrtf(u2sh[h] * v2);
        logit[h] = (nh[h] / (den + EPS)) * bsh[h];
    }

    // softmax over m (= thread index), per head; 2 waves -> shuffle + LDS combine
    const int lane = t & 63;
    const int wid  = t >> 6;

    float mx[NH];
#pragma unroll
    for (int h = 0; h < NH; ++h) {
        float m_ = logit[h];
#pragma unroll
        for (int off = 1; off < 64; off <<= 1)
            m_ = fmaxf(m_, __shfl_xor(m_, off, 64));
        mx[h] = m_;
    }
    if (lane == 0) {
#pragma unroll
        for (int h = 0; h < NH; ++h) red[wid][h] = mx[h];
    }
    __syncthreads();

    float e[NH];
#pragma unroll
    for (int h = 0; h < NH; ++h) {
        const float gm = fmaxf(red[0][h], red[1][h]);
        e[h] = expf(logit[h] - gm);
    }
    __syncthreads();  // everyone done reading red before it is overwritten

    float sm[NH];
#pragma unroll
    for (int h = 0; h < NH; ++h) {
        float s_ = e[h];
#pragma unroll
        for (int off = 1; off < 64; off <<= 1)
            s_ += __shfl_xor(s_, off, 64);
        sm[h] = s_;
    }
    if (lane == 0) {
#pragma unroll
        for (int h = 0; h < NH; ++h) red[wid][h] = sm[h];
    }
    __syncthreads();

#pragma unroll
    for (int h = 0; h < NH; ++h) {
        const float tot = red[0][h] + red[1][h];
        out[(size_t)b * (NH * M) + (size_t)h * M + t] = e[h] / tot;
    }
}

// ---------------------------------------------------------------------------
extern "C" void kernel_launch(void* const* d_in, const int* in_sizes, int n_in,
                              void* d_out, int out_size, void* d_ws, size_t ws_size,
                              hipStream_t stream) {
    const float* hid = (const float*)d_in[0];  // [B, D]
    const float* mem = (const float*)d_in[1];  // [B, M, W]
    const float* Wk  = (const float*)d_in[2];  // [D, HW]
    const float* bk  = (const float*)d_in[3];  // [HW]
    const float* Wb  = (const float*)d_in[4];  // [D, NH]
    const float* bb  = (const float*)d_in[5];  // [NH]
    float* out = (float*)d_out;                // [B, NH, M]

    float* key_ws  = (float*)d_ws;                    // B*HW floats (8 MB)
    float* beta_ws = key_ws + (size_t)B * HW;         // B*NH floats

    key_beta_gemm<<<B / 16, 256, 0, stream>>>(hid, Wk, bk, Wb, bb, key_ws, beta_ws);
    attn_kernel<<<B, 128, 0, stream>>>(mem, key_ws, beta_ws, out);
}